// Round 22
// baseline (96.054 us; speedup 1.0000x reference)
//
#include <hip/hip_runtime.h>
#include <hip/hip_bf16.h>

#define D_ 64
#define HW_ 4096
#define K_ 1024
#define NPTS_ 65536
#define QOUT_ 4194304      // B*D*H*W, offset of idx region in d_out
#define DELTA 0.006f       // ambiguity margin; worst-case bf16-split diff ~2e-3
#define INF_ 3.4e38f

typedef short bf16x8 __attribute__((ext_vector_type(8)));
typedef float f32x4 __attribute__((ext_vector_type(4)));

__device__ __forceinline__ void gload_lds16(const float* g, float* l) {
    __builtin_amdgcn_global_load_lds((const __attribute__((address_space(1))) void*)g,
                                     (__attribute__((address_space(3))) void*)l, 16, 0, 0);
}
__device__ __forceinline__ void gload_lds4(const float* g, float* l) {
    __builtin_amdgcn_global_load_lds((const __attribute__((address_space(1))) void*)g,
                                     (__attribute__((address_space(3))) void*)l, 4, 0, 0);
}

// ---- pack kernel: cnorm + bf16 hi/lo split of (-2*cb) in MFMA-fragment order ----
// P layout (shorts): [gch(64)][frag(4)][lane(64)][8]
//   code j = gch*16 + (l&15), dims d = (frag>>1)*32 + (l>>4)*8 + i, lvl = frag&1
__global__ __launch_bounds__(64) void vq_pack(const float* __restrict__ cb,
                                              float* __restrict__ cnorm,
                                              short* __restrict__ P) {
    const int t = blockIdx.x * 64 + threadIdx.x;    // 0..4095, 64 blocks
    const int gch = t >> 6, l = t & 63;
    const int j  = gch * 16 + (l & 15);
    const int dg = l >> 4;
#pragma unroll
    for (int s = 0; s < 2; ++s) {
        const float* src = cb + j * D_ + s * 32 + dg * 8;
        short hb[8], lb[8];
#pragma unroll
        for (int i = 0; i < 8; ++i) {
            const float v = -2.f * src[i];
            __hip_bfloat16 h = __float2bfloat16(v);
            hb[i] = *(const short*)&h;
            const float r = v - __bfloat162float(h);
            __hip_bfloat16 lo = __float2bfloat16(r);
            lb[i] = *(const short*)&lo;
        }
        short* dh = P + ((size_t)(gch * 4 + s * 2 + 0) * 64 + l) * 8;
        short* dl = P + ((size_t)(gch * 4 + s * 2 + 1) * 64 + l) * 8;
#pragma unroll
        for (int i = 0; i < 8; ++i) { dh[i] = hb[i]; dl[i] = lb[i]; }
    }
    if (t < K_) {
        const float4* r = (const float4*)(cb + (size_t)t * D_);
        float s0 = 0.f, s1 = 0.f, s2 = 0.f, s3 = 0.f;
#pragma unroll
        for (int i = 0; i < 16; ++i) {
            float4 v = r[i];
            s0 = fmaf(v.x, v.x, s0); s1 = fmaf(v.y, v.y, s1);
            s2 = fmaf(v.z, v.z, s2); s3 = fmaf(v.w, v.w, s3);
        }
        cnorm[t] = (s0 + s1) + (s2 + s3);
    }
}

// ---- main: R12's HW-proven 43.5us search kernel, VERBATIM ----
// 1024 blocks x 256 thr (4 waves x 16 pts). 32 chunks of 32 codes,
// double-buffered (2x8KB). NO rescan code here (R21 lesson: xv[64]'s scratch
// allocation throttles occupancy 34->22% and costs ~27us). Sign-encoded idx.
// Tripwire: VGPR must stay ~32.
__global__ __launch_bounds__(256, 4) void vq_main(const float* __restrict__ x,
                                                  const float* __restrict__ cnorm_g,
                                                  const short* __restrict__ P,
                                                  float* __restrict__ out) {
    __shared__ short cbuf[2][4096];   // 2 x 8 KB: 32 codes per buffer
    __shared__ float cnt[K_];         // 4 KB

    const int tid  = threadIdx.x;
    const int lane = tid & 63;
    const int wid  = tid >> 6;        // 0..3
    const int pg   = blockIdx.x;      // 0..1023
    const int bb   = pg >> 6;
    const int hw0  = (pg & 63) << 6;

    const float* Pf = (const float*)P;

    // stage cnorm (4 KB) + chunk 0 (8 KB)
#pragma unroll
    for (int i = 0; i < 4; ++i)
        gload_lds4(cnorm_g + i * 256 + wid * 64 + lane, cnt + i * 256 + wid * 64);
#pragma unroll
    for (int r = 0; r < 2; ++r)
        gload_lds16(Pf + r * 1024 + wid * 256 + lane * 4,
                    (float*)cbuf[0] + r * 1024 + wid * 256);

    // load + split x fragment: wave owns 16 points, lane holds point (l&15)
    bf16x8 ah[2], al[2];
    {
        const float* xb = x + (size_t)bb * (D_ * HW_) + hw0;
        const int p_l = wid * 16 + (lane & 15);
#pragma unroll
        for (int s = 0; s < 2; ++s) {
            const int d0 = s * 32 + (lane >> 4) * 8;
#pragma unroll
            for (int i = 0; i < 8; ++i) {
                const float v = xb[(size_t)(d0 + i) * HW_ + p_l];
                __hip_bfloat16 h = __float2bfloat16(v);
                ah[s][i] = *(const short*)&h;
                const float r = v - __bfloat162float(h);
                __hip_bfloat16 lo = __float2bfloat16(r);
                al[s][i] = *(const short*)&lo;
            }
        }
    }
    asm volatile("s_waitcnt vmcnt(0)" ::: "memory");
    __syncthreads();

    float m1[4], m2[4];
    int   i1[4];
#pragma unroll
    for (int q = 0; q < 4; ++q) { m1[q] = INF_; m2[q] = INF_; i1[q] = 0; }

    int cur = 0;
#pragma unroll 1
    for (int c = 0; c < 32; ++c) {
        // prefetch next chunk first: lands under this chunk's compute
        if (c + 1 < 32) {
            const float* src = Pf + (size_t)(c + 1) * 2048;
            float* dst = (float*)cbuf[cur ^ 1];
#pragma unroll
            for (int r = 0; r < 2; ++r)
                gload_lds16(src + r * 1024 + wid * 256 + lane * 4,
                            dst + r * 1024 + wid * 256);
        }
        const bf16x8* fr = (const bf16x8*)cbuf[cur];
#pragma unroll
        for (int u = 0; u < 2; ++u) {
            const int kc = c * 32 + u * 16 + (lane & 15);
            const float cn = cnt[kc];
            bf16x8 bh0 = fr[(u * 4 + 0) * 64 + lane];
            bf16x8 bl0 = fr[(u * 4 + 1) * 64 + lane];
            bf16x8 bh1 = fr[(u * 4 + 2) * 64 + lane];
            bf16x8 bl1 = fr[(u * 4 + 3) * 64 + lane];
            f32x4 aa = {0.f, 0.f, 0.f, 0.f};   // dims 0-31 (3-deep chain)
            f32x4 ab = {0.f, 0.f, 0.f, 0.f};   // dims 32-63 (3-deep chain)
            aa = __builtin_amdgcn_mfma_f32_16x16x32_bf16(ah[0], bh0, aa, 0, 0, 0);
            ab = __builtin_amdgcn_mfma_f32_16x16x32_bf16(ah[1], bh1, ab, 0, 0, 0);
            aa = __builtin_amdgcn_mfma_f32_16x16x32_bf16(al[0], bh0, aa, 0, 0, 0);
            ab = __builtin_amdgcn_mfma_f32_16x16x32_bf16(al[1], bh1, ab, 0, 0, 0);
            aa = __builtin_amdgcn_mfma_f32_16x16x32_bf16(ah[0], bl0, aa, 0, 0, 0);
            ab = __builtin_amdgcn_mfma_f32_16x16x32_bf16(ah[1], bl1, ab, 0, 0, 0);
#pragma unroll
            for (int r = 0; r < 4; ++r) {
                const float d2 = cn + (aa[r] + ab[r]);
                const bool lt = d2 < m1[r];
                m2[r] = fminf(m2[r], fmaxf(m1[r], d2));  // min(m2, loser)
                m1[r] = fminf(m1[r], d2);
                i1[r] = lt ? kc : i1[r];
            }
        }
        __syncthreads();   // prefetch complete + all waves done reading cur
        cur ^= 1;
    }

    // cross-lane (m1,i1,m2) reduce over the 16 lanes sharing (lane>>4),
    // then write FINAL idx with ambiguity flag in the sign.
#pragma unroll
    for (int q = 0; q < 4; ++q) {
        float a1 = m1[q], a2 = m2[q];
        int   ai = i1[q];
#pragma unroll
        for (int m = 1; m < 16; m <<= 1) {
            const float o1 = __shfl_xor(a1, m);
            const int   oi = __shfl_xor(ai, m);
            const float o2 = __shfl_xor(a2, m);
            const float nm2 = fminf(fminf(a2, o2), fmaxf(a1, o1));
            if (o1 < a1 || (o1 == a1 && oi < ai)) { a1 = o1; ai = oi; }
            a2 = nm2;
        }
        if ((lane & 15) == 0) {
            const int pt = wid * 16 + 4 * (lane >> 4) + q;
            const bool amb = (a2 - a1 <= DELTA);
            out[(size_t)QOUT_ + pg * 64 + pt] = amb ? -(float)(ai + 1) : (float)ai;
        }
    }
}

// ---- fix: decode sign-flagged idx, exact fp32 rescan for the ~50 flagged
// points chip-wide. 256 blocks; ~99% of waves exit after one coalesced read.
// The scratch-hungry xv[64] lives HERE, where occupancy doesn't matter.
__global__ __launch_bounds__(256) void vq_fix(const float* __restrict__ x,
                                              const float* __restrict__ cb,
                                              const float* __restrict__ cnorm_g,
                                              float* __restrict__ out) {
    const int tid  = threadIdx.x;
    const int lane = tid & 63;
    const int p    = blockIdx.x * 256 + tid;
    const int pw0  = blockIdx.x * 256 + (tid & ~63);   // wave's base point

    const float v = out[(size_t)QOUT_ + p];
    unsigned long long mask = __ballot(v < 0.f);
    while (mask) {
        const int src = __builtin_ctzll(mask);
        mask &= mask - 1;
        const int pt = pw0 + src;
        const int bb = pt >> 12;
        const int hw = pt & 4095;
        const float* xr = x + (size_t)bb * (D_ * HW_) + hw;
        float xv[D_];
#pragma unroll
        for (int d = 0; d < D_; ++d) xv[d] = xr[(size_t)d * HW_];   // wave-uniform
        float b1 = INF_; int bi = 0;
        for (int cc = 0; cc < 16; ++cc) {
            const int row = lane * 16 + cc;
            const float4* cr = (const float4*)(cb + (size_t)row * D_);
            float a0 = 0.f, a1 = 0.f, a2 = 0.f, a3 = 0.f;
#pragma unroll
            for (int g = 0; g < 16; ++g) {
                const float4 cf = cr[g];
                a0 = fmaf(xv[4 * g + 0], cf.x, a0);
                a1 = fmaf(xv[4 * g + 1], cf.y, a1);
                a2 = fmaf(xv[4 * g + 2], cf.z, a2);
                a3 = fmaf(xv[4 * g + 3], cf.w, a3);
            }
            const float dot = (a0 + a1) + (a2 + a3);
            const float d2 = fmaf(-2.f, dot, cnorm_g[row]);
            if (d2 < b1) { b1 = d2; bi = row; }
        }
#pragma unroll
        for (int m = 1; m < 64; m <<= 1) {
            const float o1 = __shfl_xor(b1, m);
            const int   oi = __shfl_xor(bi, m);
            if (o1 < b1 || (o1 == b1 && oi < bi)) { b1 = o1; bi = oi; }
        }
        if (lane == 0) out[(size_t)QOUT_ + pt] = (float)bi;
    }
}

// ---- write: element-parallel gather of quantized output ----
// One thread per output float4. 4096 blocks. idx read coalesced; cb gathers
// L2-resident; stores 1 KB/wave-instr contiguous. Runs after vq_fix (stream
// order) so all idx are clean.
__global__ __launch_bounds__(256) void vq_write(const float* __restrict__ cb,
                                                float* __restrict__ out) {
    const int e = blockIdx.x * 256 + threadIdx.x;    // 0..1048575
    const int b = e >> 16;
    const int r = e & 65535;
    const int d = r >> 10;
    const int g = r & 1023;
    const float4 fi = *(const float4*)(out + (size_t)QOUT_ + b * HW_ + g * 4);
    float4 q;
    q.x = cb[(size_t)((int)fi.x) * D_ + d];
    q.y = cb[(size_t)((int)fi.y) * D_ + d];
    q.z = cb[(size_t)((int)fi.z) * D_ + d];
    q.w = cb[(size_t)((int)fi.w) * D_ + d];
    *(float4*)(out + ((size_t)b * D_ + d) * HW_ + g * 4) = q;
}

extern "C" void kernel_launch(void* const* d_in, const int* in_sizes, int n_in,
                              void* d_out, int out_size, void* d_ws, size_t ws_size,
                              hipStream_t stream) {
    const float* x  = (const float*)d_in[0];   // (16, 64, 64, 64)
    const float* cb = (const float*)d_in[1];   // (1024, 64)
    float* out   = (float*)d_out;
    float* cnorm = (float*)d_ws;                       // 4 KB
    short* P     = (short*)((char*)d_ws + 4096);       // 256 KB packed bf16 codebook

    vq_pack<<<64, 64, 0, stream>>>(cb, cnorm, P);
    vq_main<<<NPTS_ / 64, 256, 0, stream>>>(x, cnorm, P, out);
    vq_fix<<<NPTS_ / 256, 256, 0, stream>>>(x, cb, cnorm, out);
    vq_write<<<(NPTS_ * D_ / 4) / 256, 256, 0, stream>>>(cb, out);
}

// Round 23
// 90.802 us; speedup vs baseline: 1.0578x; 1.0578x over previous
//
#include <hip/hip_runtime.h>
#include <hip/hip_bf16.h>

#define D_ 64
#define HW_ 4096
#define K_ 1024
#define NPTS_ 65536
#define QOUT_ 4194304      // B*D*H*W, offset of idx region in d_out
#define DELTA 0.006f       // ambiguity margin; worst-case bf16-split diff ~2e-3
#define INF_ 3.4e38f

typedef short bf16x8 __attribute__((ext_vector_type(8)));
typedef float f32x4 __attribute__((ext_vector_type(4)));

__device__ __forceinline__ void gload_lds16(const float* g, float* l) {
    __builtin_amdgcn_global_load_lds((const __attribute__((address_space(1))) void*)g,
                                     (__attribute__((address_space(3))) void*)l, 16, 0, 0);
}
__device__ __forceinline__ void gload_lds4(const float* g, float* l) {
    __builtin_amdgcn_global_load_lds((const __attribute__((address_space(1))) void*)g,
                                     (__attribute__((address_space(3))) void*)l, 4, 0, 0);
}

// ---- pack kernel: cnorm + bf16 hi/lo split of (-2*cb) in MFMA-fragment order ----
// P layout (shorts): [gch(64)][frag(4)][lane(64)][8]
//   code j = gch*16 + (l&15), dims d = (frag>>1)*32 + (l>>4)*8 + i, lvl = frag&1
__global__ __launch_bounds__(64) void vq_pack(const float* __restrict__ cb,
                                              float* __restrict__ cnorm,
                                              short* __restrict__ P) {
    const int t = blockIdx.x * 64 + threadIdx.x;    // 0..4095, 64 blocks
    const int gch = t >> 6, l = t & 63;
    const int j  = gch * 16 + (l & 15);
    const int dg = l >> 4;
#pragma unroll
    for (int s = 0; s < 2; ++s) {
        const float* src = cb + j * D_ + s * 32 + dg * 8;
        short hb[8], lb[8];
#pragma unroll
        for (int i = 0; i < 8; ++i) {
            const float v = -2.f * src[i];
            __hip_bfloat16 h = __float2bfloat16(v);
            hb[i] = *(const short*)&h;
            const float r = v - __bfloat162float(h);
            __hip_bfloat16 lo = __float2bfloat16(r);
            lb[i] = *(const short*)&lo;
        }
        short* dh = P + ((size_t)(gch * 4 + s * 2 + 0) * 64 + l) * 8;
        short* dl = P + ((size_t)(gch * 4 + s * 2 + 1) * 64 + l) * 8;
#pragma unroll
        for (int i = 0; i < 8; ++i) { dh[i] = hb[i]; dl[i] = lb[i]; }
    }
    if (t < K_) {
        const float4* r = (const float4*)(cb + (size_t)t * D_);
        float s0 = 0.f, s1 = 0.f, s2 = 0.f, s3 = 0.f;
#pragma unroll
        for (int i = 0; i < 16; ++i) {
            float4 v = r[i];
            s0 = fmaf(v.x, v.x, s0); s1 = fmaf(v.y, v.y, s1);
            s2 = fmaf(v.z, v.z, s2); s3 = fmaf(v.w, v.w, s3);
        }
        cnorm[t] = (s0 + s1) + (s2 + s3);
    }
}

// ---- main: R12's HW-proven 43.5us search kernel, VERBATIM ----
// 1024 blocks x 256 thr (4 waves x 16 pts). 32 chunks of 32 codes,
// double-buffered (2x8KB). No rescan code (R21: its scratch throttles
// occupancy). Sign-encoded idx. Tripwire: VGPR ~32.
__global__ __launch_bounds__(256, 4) void vq_main(const float* __restrict__ x,
                                                  const float* __restrict__ cnorm_g,
                                                  const short* __restrict__ P,
                                                  float* __restrict__ out) {
    __shared__ short cbuf[2][4096];   // 2 x 8 KB: 32 codes per buffer
    __shared__ float cnt[K_];         // 4 KB

    const int tid  = threadIdx.x;
    const int lane = tid & 63;
    const int wid  = tid >> 6;        // 0..3
    const int pg   = blockIdx.x;      // 0..1023
    const int bb   = pg >> 6;
    const int hw0  = (pg & 63) << 6;

    const float* Pf = (const float*)P;

    // stage cnorm (4 KB) + chunk 0 (8 KB)
#pragma unroll
    for (int i = 0; i < 4; ++i)
        gload_lds4(cnorm_g + i * 256 + wid * 64 + lane, cnt + i * 256 + wid * 64);
#pragma unroll
    for (int r = 0; r < 2; ++r)
        gload_lds16(Pf + r * 1024 + wid * 256 + lane * 4,
                    (float*)cbuf[0] + r * 1024 + wid * 256);

    // load + split x fragment: wave owns 16 points, lane holds point (l&15)
    bf16x8 ah[2], al[2];
    {
        const float* xb = x + (size_t)bb * (D_ * HW_) + hw0;
        const int p_l = wid * 16 + (lane & 15);
#pragma unroll
        for (int s = 0; s < 2; ++s) {
            const int d0 = s * 32 + (lane >> 4) * 8;
#pragma unroll
            for (int i = 0; i < 8; ++i) {
                const float v = xb[(size_t)(d0 + i) * HW_ + p_l];
                __hip_bfloat16 h = __float2bfloat16(v);
                ah[s][i] = *(const short*)&h;
                const float r = v - __bfloat162float(h);
                __hip_bfloat16 lo = __float2bfloat16(r);
                al[s][i] = *(const short*)&lo;
            }
        }
    }
    asm volatile("s_waitcnt vmcnt(0)" ::: "memory");
    __syncthreads();

    float m1[4], m2[4];
    int   i1[4];
#pragma unroll
    for (int q = 0; q < 4; ++q) { m1[q] = INF_; m2[q] = INF_; i1[q] = 0; }

    int cur = 0;
#pragma unroll 1
    for (int c = 0; c < 32; ++c) {
        // prefetch next chunk first: lands under this chunk's compute
        if (c + 1 < 32) {
            const float* src = Pf + (size_t)(c + 1) * 2048;
            float* dst = (float*)cbuf[cur ^ 1];
#pragma unroll
            for (int r = 0; r < 2; ++r)
                gload_lds16(src + r * 1024 + wid * 256 + lane * 4,
                            dst + r * 1024 + wid * 256);
        }
        const bf16x8* fr = (const bf16x8*)cbuf[cur];
#pragma unroll
        for (int u = 0; u < 2; ++u) {
            const int kc = c * 32 + u * 16 + (lane & 15);
            const float cn = cnt[kc];
            bf16x8 bh0 = fr[(u * 4 + 0) * 64 + lane];
            bf16x8 bl0 = fr[(u * 4 + 1) * 64 + lane];
            bf16x8 bh1 = fr[(u * 4 + 2) * 64 + lane];
            bf16x8 bl1 = fr[(u * 4 + 3) * 64 + lane];
            f32x4 aa = {0.f, 0.f, 0.f, 0.f};   // dims 0-31 (3-deep chain)
            f32x4 ab = {0.f, 0.f, 0.f, 0.f};   // dims 32-63 (3-deep chain)
            aa = __builtin_amdgcn_mfma_f32_16x16x32_bf16(ah[0], bh0, aa, 0, 0, 0);
            ab = __builtin_amdgcn_mfma_f32_16x16x32_bf16(ah[1], bh1, ab, 0, 0, 0);
            aa = __builtin_amdgcn_mfma_f32_16x16x32_bf16(al[0], bh0, aa, 0, 0, 0);
            ab = __builtin_amdgcn_mfma_f32_16x16x32_bf16(al[1], bh1, ab, 0, 0, 0);
            aa = __builtin_amdgcn_mfma_f32_16x16x32_bf16(ah[0], bl0, aa, 0, 0, 0);
            ab = __builtin_amdgcn_mfma_f32_16x16x32_bf16(ah[1], bl1, ab, 0, 0, 0);
#pragma unroll
            for (int r = 0; r < 4; ++r) {
                const float d2 = cn + (aa[r] + ab[r]);
                const bool lt = d2 < m1[r];
                m2[r] = fminf(m2[r], fmaxf(m1[r], d2));  // min(m2, loser)
                m1[r] = fminf(m1[r], d2);
                i1[r] = lt ? kc : i1[r];
            }
        }
        __syncthreads();   // prefetch complete + all waves done reading cur
        cur ^= 1;
    }

    // cross-lane (m1,i1,m2) reduce over the 16 lanes sharing (lane>>4),
    // then write FINAL idx with ambiguity flag in the sign.
#pragma unroll
    for (int q = 0; q < 4; ++q) {
        float a1 = m1[q], a2 = m2[q];
        int   ai = i1[q];
#pragma unroll
        for (int m = 1; m < 16; m <<= 1) {
            const float o1 = __shfl_xor(a1, m);
            const int   oi = __shfl_xor(ai, m);
            const float o2 = __shfl_xor(a2, m);
            const float nm2 = fminf(fminf(a2, o2), fmaxf(a1, o1));
            if (o1 < a1 || (o1 == a1 && oi < ai)) { a1 = o1; ai = oi; }
            a2 = nm2;
        }
        if ((lane & 15) == 0) {
            const int pt = wid * 16 + 4 * (lane >> 4) + q;
            const bool amb = (a2 - a1 <= DELTA);
            out[(size_t)QOUT_ + pg * 64 + pt] = amb ? -(float)(ai + 1) : (float)ai;
        }
    }
}

// ---- fix: exact fp32 rescan of sign-flagged points (~50 chip-wide) ----
// R22 failure: per-lane xv[64] went to scratch -> ~1024 serialized scratch
// reads = 48us for ONE rescan. Fix: stage x into a per-wave LDS slot (one
// strided 64-lane load), dot-loop reads x via LDS BROADCAST (same addr all
// lanes = conflict-free). Tripwire: VGPR >= 56 = scratch leaked back.
__global__ __launch_bounds__(256) void vq_fix(const float* __restrict__ x,
                                              const float* __restrict__ cb,
                                              const float* __restrict__ cnorm_g,
                                              float* __restrict__ out) {
    __shared__ float xs[4][64];       // per-wave x-point slot

    const int tid  = threadIdx.x;
    const int lane = tid & 63;
    const int wv   = tid >> 6;
    const int p    = blockIdx.x * 256 + tid;
    const int pw0  = blockIdx.x * 256 + (tid & ~63);   // wave's base point

    const float v = out[(size_t)QOUT_ + p];
    unsigned long long mask = __ballot(v < 0.f);
    while (mask) {
        const int src = __builtin_ctzll(mask);
        mask &= mask - 1;
        const int pt = pw0 + src;
        const int bb = pt >> 12;
        const int hw = pt & 4095;
        // stage the point's 64 dims: lane d loads x[bb, d, hw]
        xs[wv][lane] = x[(size_t)bb * (D_ * HW_) + (size_t)lane * HW_ + hw];
        float b1 = INF_; int bi = 0;
        for (int cc = 0; cc < 16; ++cc) {
            const int row = lane * 16 + cc;
            const float4* cr = (const float4*)(cb + (size_t)row * D_);
            float a0 = 0.f, a1 = 0.f, a2 = 0.f, a3 = 0.f;
#pragma unroll
            for (int g = 0; g < 16; ++g) {
                const float4 cf = cr[g];
                a0 = fmaf(xs[wv][4 * g + 0], cf.x, a0);   // LDS broadcast reads
                a1 = fmaf(xs[wv][4 * g + 1], cf.y, a1);
                a2 = fmaf(xs[wv][4 * g + 2], cf.z, a2);
                a3 = fmaf(xs[wv][4 * g + 3], cf.w, a3);
            }
            const float dot = (a0 + a1) + (a2 + a3);
            const float d2 = fmaf(-2.f, dot, cnorm_g[row]);
            if (d2 < b1) { b1 = d2; bi = row; }
        }
#pragma unroll
        for (int m = 1; m < 64; m <<= 1) {
            const float o1 = __shfl_xor(b1, m);
            const int   oi = __shfl_xor(bi, m);
            if (o1 < b1 || (o1 == b1 && oi < bi)) { b1 = o1; bi = oi; }
        }
        if (lane == 0) out[(size_t)QOUT_ + pt] = (float)bi;
    }
}

// ---- write: element-parallel gather of quantized output ----
// One thread per output float4. 4096 blocks. idx read coalesced; cb gathers
// L2-resident; stores 1 KB/wave-instr contiguous. Runs after vq_fix.
__global__ __launch_bounds__(256) void vq_write(const float* __restrict__ cb,
                                                float* __restrict__ out) {
    const int e = blockIdx.x * 256 + threadIdx.x;    // 0..1048575
    const int b = e >> 16;
    const int r = e & 65535;
    const int d = r >> 10;
    const int g = r & 1023;
    const float4 fi = *(const float4*)(out + (size_t)QOUT_ + b * HW_ + g * 4);
    float4 q;
    q.x = cb[(size_t)((int)fi.x) * D_ + d];
    q.y = cb[(size_t)((int)fi.y) * D_ + d];
    q.z = cb[(size_t)((int)fi.z) * D_ + d];
    q.w = cb[(size_t)((int)fi.w) * D_ + d];
    *(float4*)(out + ((size_t)b * D_ + d) * HW_ + g * 4) = q;
}

extern "C" void kernel_launch(void* const* d_in, const int* in_sizes, int n_in,
                              void* d_out, int out_size, void* d_ws, size_t ws_size,
                              hipStream_t stream) {
    const float* x  = (const float*)d_in[0];   // (16, 64, 64, 64)
    const float* cb = (const float*)d_in[1];   // (1024, 64)
    float* out   = (float*)d_out;
    float* cnorm = (float*)d_ws;                       // 4 KB
    short* P     = (short*)((char*)d_ws + 4096);       // 256 KB packed bf16 codebook

    vq_pack<<<64, 64, 0, stream>>>(cb, cnorm, P);
    vq_main<<<NPTS_ / 64, 256, 0, stream>>>(x, cnorm, P, out);
    vq_fix<<<NPTS_ / 256, 256, 0, stream>>>(x, cb, cnorm, out);
    vq_write<<<(NPTS_ * D_ / 4) / 256, 256, 0, stream>>>(cb, out);
}

// Round 24
// 71.114 us; speedup vs baseline: 1.3507x; 1.2768x over previous
//
#include <hip/hip_runtime.h>
#include <hip/hip_bf16.h>

#define D_ 64
#define HW_ 4096
#define K_ 1024
#define NPTS_ 65536
#define QOUT_ 4194304      // B*D*H*W, offset of idx region in d_out
#define DELTA 0.006f       // ambiguity margin; worst-case bf16-split diff ~2e-3
#define INF_ 3.4e38f

typedef short bf16x8 __attribute__((ext_vector_type(8)));
typedef float f32x4 __attribute__((ext_vector_type(4)));

__device__ __forceinline__ void gload_lds16(const float* g, float* l) {
    __builtin_amdgcn_global_load_lds((const __attribute__((address_space(1))) void*)g,
                                     (__attribute__((address_space(3))) void*)l, 16, 0, 0);
}
__device__ __forceinline__ void gload_lds4(const float* g, float* l) {
    __builtin_amdgcn_global_load_lds((const __attribute__((address_space(1))) void*)g,
                                     (__attribute__((address_space(3))) void*)l, 4, 0, 0);
}

// ---- pack kernel: cnorm + bf16 hi/lo split of (-2*cb) in MFMA-fragment order ----
// Also zeroes the flag counter (out[0]) each launch (deterministic replays).
__global__ __launch_bounds__(64) void vq_pack(const float* __restrict__ cb,
                                              float* __restrict__ cnorm,
                                              short* __restrict__ P,
                                              float* __restrict__ out) {
    if (blockIdx.x == 0 && threadIdx.x == 0) *(int*)out = 0;   // flag counter
    const int t = blockIdx.x * 64 + threadIdx.x;    // 0..4095, 64 blocks
    const int gch = t >> 6, l = t & 63;
    const int j  = gch * 16 + (l & 15);
    const int dg = l >> 4;
#pragma unroll
    for (int s = 0; s < 2; ++s) {
        const float* src = cb + j * D_ + s * 32 + dg * 8;
        short hb[8], lb[8];
#pragma unroll
        for (int i = 0; i < 8; ++i) {
            const float v = -2.f * src[i];
            __hip_bfloat16 h = __float2bfloat16(v);
            hb[i] = *(const short*)&h;
            const float r = v - __bfloat162float(h);
            __hip_bfloat16 lo = __float2bfloat16(r);
            lb[i] = *(const short*)&lo;
        }
        short* dh = P + ((size_t)(gch * 4 + s * 2 + 0) * 64 + l) * 8;
        short* dl = P + ((size_t)(gch * 4 + s * 2 + 1) * 64 + l) * 8;
#pragma unroll
        for (int i = 0; i < 8; ++i) { dh[i] = hb[i]; dl[i] = lb[i]; }
    }
    if (t < K_) {
        const float4* r = (const float4*)(cb + (size_t)t * D_);
        float s0 = 0.f, s1 = 0.f, s2 = 0.f, s3 = 0.f;
#pragma unroll
        for (int i = 0; i < 16; ++i) {
            float4 v = r[i];
            s0 = fmaf(v.x, v.x, s0); s1 = fmaf(v.y, v.y, s1);
            s2 = fmaf(v.z, v.z, s2); s3 = fmaf(v.w, v.w, s3);
        }
        cnorm[t] = (s0 + s1) + (s2 + s3);
    }
}

// ---- main: R12's HW-proven 43.5us search kernel, VERBATIM ----
// 1024 blocks x 256 thr (4 waves x 16 pts). 32 chunks of 32 codes,
// double-buffered (2x8KB). Sign-encoded idx. Tripwire: VGPR ~32.
__global__ __launch_bounds__(256, 4) void vq_main(const float* __restrict__ x,
                                                  const float* __restrict__ cnorm_g,
                                                  const short* __restrict__ P,
                                                  float* __restrict__ out) {
    __shared__ short cbuf[2][4096];   // 2 x 8 KB: 32 codes per buffer
    __shared__ float cnt[K_];         // 4 KB

    const int tid  = threadIdx.x;
    const int lane = tid & 63;
    const int wid  = tid >> 6;        // 0..3
    const int pg   = blockIdx.x;      // 0..1023
    const int bb   = pg >> 6;
    const int hw0  = (pg & 63) << 6;

    const float* Pf = (const float*)P;

    // stage cnorm (4 KB) + chunk 0 (8 KB)
#pragma unroll
    for (int i = 0; i < 4; ++i)
        gload_lds4(cnorm_g + i * 256 + wid * 64 + lane, cnt + i * 256 + wid * 64);
#pragma unroll
    for (int r = 0; r < 2; ++r)
        gload_lds16(Pf + r * 1024 + wid * 256 + lane * 4,
                    (float*)cbuf[0] + r * 1024 + wid * 256);

    // load + split x fragment: wave owns 16 points, lane holds point (l&15)
    bf16x8 ah[2], al[2];
    {
        const float* xb = x + (size_t)bb * (D_ * HW_) + hw0;
        const int p_l = wid * 16 + (lane & 15);
#pragma unroll
        for (int s = 0; s < 2; ++s) {
            const int d0 = s * 32 + (lane >> 4) * 8;
#pragma unroll
            for (int i = 0; i < 8; ++i) {
                const float v = xb[(size_t)(d0 + i) * HW_ + p_l];
                __hip_bfloat16 h = __float2bfloat16(v);
                ah[s][i] = *(const short*)&h;
                const float r = v - __bfloat162float(h);
                __hip_bfloat16 lo = __float2bfloat16(r);
                al[s][i] = *(const short*)&lo;
            }
        }
    }
    asm volatile("s_waitcnt vmcnt(0)" ::: "memory");
    __syncthreads();

    float m1[4], m2[4];
    int   i1[4];
#pragma unroll
    for (int q = 0; q < 4; ++q) { m1[q] = INF_; m2[q] = INF_; i1[q] = 0; }

    int cur = 0;
#pragma unroll 1
    for (int c = 0; c < 32; ++c) {
        if (c + 1 < 32) {
            const float* src = Pf + (size_t)(c + 1) * 2048;
            float* dst = (float*)cbuf[cur ^ 1];
#pragma unroll
            for (int r = 0; r < 2; ++r)
                gload_lds16(src + r * 1024 + wid * 256 + lane * 4,
                            dst + r * 1024 + wid * 256);
        }
        const bf16x8* fr = (const bf16x8*)cbuf[cur];
#pragma unroll
        for (int u = 0; u < 2; ++u) {
            const int kc = c * 32 + u * 16 + (lane & 15);
            const float cn = cnt[kc];
            bf16x8 bh0 = fr[(u * 4 + 0) * 64 + lane];
            bf16x8 bl0 = fr[(u * 4 + 1) * 64 + lane];
            bf16x8 bh1 = fr[(u * 4 + 2) * 64 + lane];
            bf16x8 bl1 = fr[(u * 4 + 3) * 64 + lane];
            f32x4 aa = {0.f, 0.f, 0.f, 0.f};   // dims 0-31 (3-deep chain)
            f32x4 ab = {0.f, 0.f, 0.f, 0.f};   // dims 32-63 (3-deep chain)
            aa = __builtin_amdgcn_mfma_f32_16x16x32_bf16(ah[0], bh0, aa, 0, 0, 0);
            ab = __builtin_amdgcn_mfma_f32_16x16x32_bf16(ah[1], bh1, ab, 0, 0, 0);
            aa = __builtin_amdgcn_mfma_f32_16x16x32_bf16(al[0], bh0, aa, 0, 0, 0);
            ab = __builtin_amdgcn_mfma_f32_16x16x32_bf16(al[1], bh1, ab, 0, 0, 0);
            aa = __builtin_amdgcn_mfma_f32_16x16x32_bf16(ah[0], bl0, aa, 0, 0, 0);
            ab = __builtin_amdgcn_mfma_f32_16x16x32_bf16(ah[1], bl1, ab, 0, 0, 0);
#pragma unroll
            for (int r = 0; r < 4; ++r) {
                const float d2 = cn + (aa[r] + ab[r]);
                const bool lt = d2 < m1[r];
                m2[r] = fminf(m2[r], fmaxf(m1[r], d2));  // min(m2, loser)
                m1[r] = fminf(m1[r], d2);
                i1[r] = lt ? kc : i1[r];
            }
        }
        __syncthreads();
        cur ^= 1;
    }

    // cross-lane (m1,i1,m2) reduce, then sign-flagged idx out
#pragma unroll
    for (int q = 0; q < 4; ++q) {
        float a1 = m1[q], a2 = m2[q];
        int   ai = i1[q];
#pragma unroll
        for (int m = 1; m < 16; m <<= 1) {
            const float o1 = __shfl_xor(a1, m);
            const int   oi = __shfl_xor(ai, m);
            const float o2 = __shfl_xor(a2, m);
            const float nm2 = fminf(fminf(a2, o2), fmaxf(a1, o1));
            if (o1 < a1 || (o1 == a1 && oi < ai)) { a1 = o1; ai = oi; }
            a2 = nm2;
        }
        if ((lane & 15) == 0) {
            const int pt = wid * 16 + 4 * (lane >> 4) + q;
            const bool amb = (a2 - a1 <= DELTA);
            out[(size_t)QOUT_ + pg * 64 + pt] = amb ? -(float)(ai + 1) : (float)ai;
        }
    }
}

// ---- flag: compact sign-flagged point ids into a global list ----
// List lives in the quantized region of d_out (dead until vq_write):
// counter at out[0], entries at out[1..]. ~few hundred atomics total.
__global__ __launch_bounds__(256) void vq_flag(float* __restrict__ out) {
    const int t = blockIdx.x * 256 + threadIdx.x;   // 0..16383
    const float4 v = *(const float4*)(out + (size_t)QOUT_ + t * 4);
    int* cnt  = (int*)out;
    int* list = (int*)out + 1;
#pragma unroll
    for (int j = 0; j < 4; ++j) {
        const float f = (j == 0) ? v.x : (j == 1) ? v.y : (j == 2) ? v.z : v.w;
        if (f < 0.f) { const int p = atomicAdd(cnt, 1); list[p] = t * 4 + j; }
    }
}

// ---- fix2: block-parallel exact fp32 rescan of listed points ----
// 256 blocks x 4 waves; block grid-strides the list. Per point: x staged to
// LDS once (broadcast reads), 4 waves x 4 contiguous rows/lane cover all
// 1024 codes; shfl + LDS lexicographic reduce = exact np.argmin.
__global__ __launch_bounds__(256) void vq_fix2(const float* __restrict__ x,
                                               const float* __restrict__ cb,
                                               const float* __restrict__ cnorm_g,
                                               float* __restrict__ out) {
    __shared__ float xs[64];
    __shared__ float gm[4];
    __shared__ int   gi[4];

    const int tid  = threadIdx.x;
    const int lane = tid & 63;
    const int wv   = tid >> 6;
    const int n    = *(const int*)out;
    const int* list = (const int*)out + 1;

    for (int i = blockIdx.x; i < n; i += 256) {
        const int pt = list[i];
        const int bb = pt >> 12;
        const int hw = pt & 4095;
        __syncthreads();   // previous iteration done reading xs
        if (tid < 64) xs[tid] = x[(size_t)bb * (D_ * HW_) + (size_t)tid * HW_ + hw];
        __syncthreads();

        float b1 = INF_; int bi = 0;
#pragma unroll
        for (int c = 0; c < 4; ++c) {
            const int row = wv * 256 + lane * 4 + c;       // contiguous rows/lane
            const float4* cr = (const float4*)(cb + (size_t)row * D_);
            float a0 = 0.f, a1 = 0.f, a2 = 0.f, a3 = 0.f;
#pragma unroll
            for (int g = 0; g < 16; ++g) {
                const float4 cf = cr[g];
                a0 = fmaf(xs[4 * g + 0], cf.x, a0);        // LDS broadcast
                a1 = fmaf(xs[4 * g + 1], cf.y, a1);
                a2 = fmaf(xs[4 * g + 2], cf.z, a2);
                a3 = fmaf(xs[4 * g + 3], cf.w, a3);
            }
            const float dot = (a0 + a1) + (a2 + a3);
            const float d2 = fmaf(-2.f, dot, cnorm_g[row]);
            if (d2 < b1) { b1 = d2; bi = row; }            // ascending row: first-min
        }
#pragma unroll
        for (int m = 1; m < 64; m <<= 1) {
            const float o1 = __shfl_xor(b1, m);
            const int   oi = __shfl_xor(bi, m);
            if (o1 < b1 || (o1 == b1 && oi < bi)) { b1 = o1; bi = oi; }
        }
        if (lane == 0) { gm[wv] = b1; gi[wv] = bi; }
        __syncthreads();
        if (tid == 0) {
            float f1 = gm[0]; int fi = gi[0];
#pragma unroll
            for (int w = 1; w < 4; ++w) {
                if (gm[w] < f1 || (gm[w] == f1 && gi[w] < fi)) { f1 = gm[w]; fi = gi[w]; }
            }
            out[(size_t)QOUT_ + pt] = (float)fi;
        }
    }
}

// ---- write: element-parallel gather of quantized output ----
// One thread per output float4; overwrites the list region. Runs last.
__global__ __launch_bounds__(256) void vq_write(const float* __restrict__ cb,
                                                float* __restrict__ out) {
    const int e = blockIdx.x * 256 + threadIdx.x;    // 0..1048575
    const int b = e >> 16;
    const int r = e & 65535;
    const int d = r >> 10;
    const int g = r & 1023;
    const float4 fi = *(const float4*)(out + (size_t)QOUT_ + b * HW_ + g * 4);
    float4 q;
    q.x = cb[(size_t)((int)fi.x) * D_ + d];
    q.y = cb[(size_t)((int)fi.y) * D_ + d];
    q.z = cb[(size_t)((int)fi.z) * D_ + d];
    q.w = cb[(size_t)((int)fi.w) * D_ + d];
    *(float4*)(out + ((size_t)b * D_ + d) * HW_ + g * 4) = q;
}

extern "C" void kernel_launch(void* const* d_in, const int* in_sizes, int n_in,
                              void* d_out, int out_size, void* d_ws, size_t ws_size,
                              hipStream_t stream) {
    const float* x  = (const float*)d_in[0];   // (16, 64, 64, 64)
    const float* cb = (const float*)d_in[1];   // (1024, 64)
    float* out   = (float*)d_out;
    float* cnorm = (float*)d_ws;                       // 4 KB
    short* P     = (short*)((char*)d_ws + 4096);       // 256 KB packed bf16 codebook

    vq_pack<<<64, 64, 0, stream>>>(cb, cnorm, P, out);
    vq_main<<<NPTS_ / 64, 256, 0, stream>>>(x, cnorm, P, out);
    vq_flag<<<64, 256, 0, stream>>>(out);
    vq_fix2<<<256, 256, 0, stream>>>(x, cb, cnorm, out);
    vq_write<<<(NPTS_ * D_ / 4) / 256, 256, 0, stream>>>(cb, out);
}

// Round 25
// 62.010 us; speedup vs baseline: 1.5490x; 1.1468x over previous
//
#include <hip/hip_runtime.h>
#include <hip/hip_bf16.h>

#define D_ 64
#define HW_ 4096
#define K_ 1024
#define NPTS_ 65536
#define QOUT_ 4194304      // B*D*H*W, offset of idx region in d_out
#define DELTA 0.006f       // ambiguity margin; worst-case bf16-split diff ~2e-3
#define INF_ 3.4e38f

typedef short bf16x8 __attribute__((ext_vector_type(8)));
typedef float f32x4 __attribute__((ext_vector_type(4)));

// ---- pack kernel: cnorm + bf16 hi/lo split of (-2*cb) in MFMA-fragment order ----
// P layout (shorts): [g(64)][frag(4)][lane(64)][8]
//   code j = g*16 + (l&15), dims d = (frag>>1)*32 + (l>>4)*8 + i, lvl = frag&1
__global__ __launch_bounds__(256) void vq_pack(const float* __restrict__ cb,
                                               float* __restrict__ cnorm,
                                               short* __restrict__ P) {
    const int t = blockIdx.x * 256 + threadIdx.x;   // 0..4095
    const int gch = t >> 6, l = t & 63;
    const int j  = gch * 16 + (l & 15);
    const int dg = l >> 4;
#pragma unroll
    for (int s = 0; s < 2; ++s) {
        const float* src = cb + j * D_ + s * 32 + dg * 8;
        short hb[8], lb[8];
#pragma unroll
        for (int i = 0; i < 8; ++i) {
            const float v = -2.f * src[i];
            __hip_bfloat16 h = __float2bfloat16(v);
            hb[i] = *(const short*)&h;
            const float r = v - __bfloat162float(h);
            __hip_bfloat16 lo = __float2bfloat16(r);
            lb[i] = *(const short*)&lo;
        }
        short* dh = P + ((size_t)(gch * 4 + s * 2 + 0) * 64 + l) * 8;
        short* dl = P + ((size_t)(gch * 4 + s * 2 + 1) * 64 + l) * 8;
#pragma unroll
        for (int i = 0; i < 8; ++i) { dh[i] = hb[i]; dl[i] = lb[i]; }
    }
    if (t < K_) {
        const float4* r = (const float4*)(cb + (size_t)t * D_);
        float s0 = 0.f, s1 = 0.f, s2 = 0.f, s3 = 0.f;
#pragma unroll
        for (int i = 0; i < 16; ++i) {
            float4 v = r[i];
            s0 = fmaf(v.x, v.x, s0); s1 = fmaf(v.y, v.y, s1);
            s2 = fmaf(v.z, v.z, s2); s3 = fmaf(v.w, v.w, s3);
        }
        cnorm[t] = (s0 + s1) + (s2 + s3);
    }
}

// one 16-code group step: 12 MFMAs (R14/R16-proven chain split) + min-update
#define VQ_STEP(BH0, BL0, BH1, BL1, CN, G) do {                                   \
    const int kc_ = (G) * 16 + kl;                                                \
    f32x4 a0a = {0.f,0.f,0.f,0.f}, a0b = {0.f,0.f,0.f,0.f};                       \
    f32x4 a1a = {0.f,0.f,0.f,0.f}, a1b = {0.f,0.f,0.f,0.f};                       \
    a0a = __builtin_amdgcn_mfma_f32_16x16x32_bf16(ah[0][0], BH0, a0a, 0, 0, 0);   \
    a1a = __builtin_amdgcn_mfma_f32_16x16x32_bf16(ah[1][0], BH0, a1a, 0, 0, 0);   \
    a0b = __builtin_amdgcn_mfma_f32_16x16x32_bf16(ah[0][1], BH1, a0b, 0, 0, 0);   \
    a1b = __builtin_amdgcn_mfma_f32_16x16x32_bf16(ah[1][1], BH1, a1b, 0, 0, 0);   \
    a0a = __builtin_amdgcn_mfma_f32_16x16x32_bf16(al[0][0], BH0, a0a, 0, 0, 0);   \
    a1a = __builtin_amdgcn_mfma_f32_16x16x32_bf16(al[1][0], BH0, a1a, 0, 0, 0);   \
    a0b = __builtin_amdgcn_mfma_f32_16x16x32_bf16(al[0][1], BH1, a0b, 0, 0, 0);   \
    a1b = __builtin_amdgcn_mfma_f32_16x16x32_bf16(al[1][1], BH1, a1b, 0, 0, 0);   \
    a0a = __builtin_amdgcn_mfma_f32_16x16x32_bf16(ah[0][0], BL0, a0a, 0, 0, 0);   \
    a1a = __builtin_amdgcn_mfma_f32_16x16x32_bf16(ah[1][0], BL0, a1a, 0, 0, 0);   \
    a0b = __builtin_amdgcn_mfma_f32_16x16x32_bf16(ah[0][1], BL1, a0b, 0, 0, 0);   \
    a1b = __builtin_amdgcn_mfma_f32_16x16x32_bf16(ah[1][1], BL1, a1b, 0, 0, 0);   \
    _Pragma("unroll")                                                             \
    for (int t_ = 0; t_ < 2; ++t_)                                                \
        _Pragma("unroll")                                                         \
        for (int r_ = 0; r_ < 4; ++r_) {                                          \
            const int q_ = t_ * 4 + r_;                                           \
            const float d2_ = (CN) + ((t_ == 0) ? (a0a[r_] + a0b[r_])             \
                                                : (a1a[r_] + a1b[r_]));           \
            const bool lt_ = d2_ < m1[q_];                                        \
            m2[q_] = fminf(m2[q_], fmaxf(m1[q_], d2_));                           \
            m1[q_] = fminf(m1[q_], d2_);                                          \
            i1[q_] = lt_ ? kc_ : i1[q_];                                          \
        }                                                                         \
} while (0)

// ---- fused main: BARRIER-FREE register-pipelined global-B streaming ----
// 512 blocks x 256 thr (4 waves x 32 pts). Each wave streams all 1024 codes
// in 64 groups; explicit ping-pong prefetch (B <- g+1, compute g from A,
// A <- g+2, compute g+1 from B) issues loads one full group (~300 cyc)
// ahead of use -- covers L2 latency without LDS staging or barriers.
// Best measured config of the session: 61.9 us timed, absmax 0.
__global__ __launch_bounds__(256, 2) void vq_main(const float* __restrict__ x,
                                                  const float* __restrict__ cb,
                                                  const float* __restrict__ cnorm_g,
                                                  const short* __restrict__ P,
                                                  float* __restrict__ out) {
    __shared__ float tile[128 * 65];   // 33.3 KB epilogue transpose staging
    __shared__ int res_idx[128];
    __shared__ int flist[128];
    __shared__ int fcnt;

    const int tid  = threadIdx.x;
    const int lane = tid & 63;
    const int wid  = tid >> 6;        // 0..3 = 32-pt group
    const int kl   = lane & 15;
    const int pg   = blockIdx.x;      // 0..511
    const int bb   = pg >> 5;
    const int hw0  = (pg & 31) << 7;  // 128 pts per block

    if (tid == 0) fcnt = 0;

    // x load + split: wave owns 32 points (two 16x16 A-tiles)
    bf16x8 ah[2][2], al[2][2];
    {
        const float* xb = x + (size_t)bb * (D_ * HW_) + hw0;
#pragma unroll
        for (int t = 0; t < 2; ++t) {
            const int p_l = wid * 32 + t * 16 + kl;
#pragma unroll
            for (int s = 0; s < 2; ++s) {
                const int d0 = s * 32 + (lane >> 4) * 8;
#pragma unroll
                for (int i = 0; i < 8; ++i) {
                    const float v = xb[(size_t)(d0 + i) * HW_ + p_l];
                    __hip_bfloat16 h = __float2bfloat16(v);
                    ah[t][s][i] = *(const short*)&h;
                    const float r = v - __bfloat162float(h);
                    __hip_bfloat16 lo = __float2bfloat16(r);
                    al[t][s][i] = *(const short*)&lo;
                }
            }
        }
    }
    __syncthreads();   // fcnt visible before flag writes

    float m1[8], m2[8];
    int   i1[8];
#pragma unroll
    for (int q = 0; q < 8; ++q) { m1[q] = INF_; m2[q] = INF_; i1[q] = 0; }

    const bf16x8* gp = (const bf16x8*)P;

    // prologue: group 0 -> A registers
    bf16x8 A0 = gp[0 * 64 + lane], A1 = gp[1 * 64 + lane];
    bf16x8 A2 = gp[2 * 64 + lane], A3 = gp[3 * 64 + lane];
    float cnA = cnorm_g[kl];
    bf16x8 B0, B1, B2, B3;
    float cnB;

#pragma unroll 1
    for (int gg = 0; gg < 32; ++gg) {
        const int g0 = gg * 2, g1 = g0 + 1, g2 = g0 + 2;
        // prefetch group g1 -> B (used after ~12 MFMA + epilogue)
        B0 = gp[(g1 * 4 + 0) * 64 + lane];
        B1 = gp[(g1 * 4 + 1) * 64 + lane];
        B2 = gp[(g1 * 4 + 2) * 64 + lane];
        B3 = gp[(g1 * 4 + 3) * 64 + lane];
        cnB = cnorm_g[g1 * 16 + kl];
        // compute group g0 from A
        VQ_STEP(A0, A1, A2, A3, cnA, g0);
        // prefetch group g2 -> A
        if (g2 < 64) {
            A0 = gp[(g2 * 4 + 0) * 64 + lane];
            A1 = gp[(g2 * 4 + 1) * 64 + lane];
            A2 = gp[(g2 * 4 + 2) * 64 + lane];
            A3 = gp[(g2 * 4 + 3) * 64 + lane];
            cnA = cnorm_g[g2 * 16 + kl];
        }
        // compute group g1 from B
        VQ_STEP(B0, B1, B2, B3, cnB, g1);
    }

    // cross-lane (m1,i1,m2) reduce over the 16 lanes sharing (lane>>4);
    // result is FINAL (wave covered all K) -> flag + store directly.
#pragma unroll
    for (int q = 0; q < 8; ++q) {
        float a1 = m1[q], a2 = m2[q];
        int   ai = i1[q];
#pragma unroll
        for (int m = 1; m < 16; m <<= 1) {
            const float o1 = __shfl_xor(a1, m);
            const int   oi = __shfl_xor(ai, m);
            const float o2 = __shfl_xor(a2, m);
            const float nm2 = fminf(fminf(a2, o2), fmaxf(a1, o1));
            if (o1 < a1 || (o1 == a1 && oi < ai)) { a1 = o1; ai = oi; }
            a2 = nm2;
        }
        if ((lane & 15) == 0) {
            const int t = q >> 2, r = q & 3;
            const int pt = wid * 32 + t * 16 + 4 * (lane >> 4) + r;
            res_idx[pt] = ai;
            if (a2 - a1 <= DELTA) { const int p = atomicAdd(&fcnt, 1); flist[p] = pt; }
        }
    }
    __syncthreads();

    // exact fp32 rescan for ambiguous points (expected ~0.1/block)
    const int nf = fcnt;
    for (int i = wid; i < nf; i += 4) {
        const int pt = flist[i];
        const float* xr = x + (size_t)bb * (D_ * HW_) + hw0 + pt;
        float xv[D_];
#pragma unroll
        for (int d = 0; d < D_; ++d) xv[d] = xr[(size_t)d * HW_];   // wave-uniform
        float b1 = INF_; int bi = 0;
        for (int cc = 0; cc < 16; ++cc) {
            const int row = lane * 16 + cc;
            const float4* cr = (const float4*)(cb + (size_t)row * D_);
            float a0 = 0.f, a1 = 0.f, a2 = 0.f, a3 = 0.f;
#pragma unroll
            for (int g = 0; g < 16; ++g) {
                const float4 cf = cr[g];
                a0 = fmaf(xv[4 * g + 0], cf.x, a0);
                a1 = fmaf(xv[4 * g + 1], cf.y, a1);
                a2 = fmaf(xv[4 * g + 2], cf.z, a2);
                a3 = fmaf(xv[4 * g + 3], cf.w, a3);
            }
            const float dot = (a0 + a1) + (a2 + a3);
            const float d2 = fmaf(-2.f, dot, cnorm_g[row]);
            if (d2 < b1) { b1 = d2; bi = row; }
        }
#pragma unroll
        for (int m = 1; m < 64; m <<= 1) {
            const float o1 = __shfl_xor(b1, m);
            const int   oi = __shfl_xor(bi, m);
            if (o1 < b1 || (o1 == b1 && oi < bi)) { b1 = o1; bi = oi; }
        }
        if (lane == 0) res_idx[pt] = bi;
    }
    __syncthreads();

    // idx output (float; exact for values <= 1023)
    if (tid < 128) out[(size_t)QOUT_ + pg * 128 + tid] = (float)res_idx[tid];

    // Phase A: gather winning rows (16 lanes x 16 B = full 256 B row each),
    // write into [pt][65] tile. Banks: pt + 4dq + j -> 2-way max (free).
#pragma unroll
    for (int pass = 0; pass < 8; ++pass) {
        const int pt = pass * 16 + (tid >> 4);
        const int dq = tid & 15;
        const float4 v = *(const float4*)(cb + (size_t)res_idx[pt] * D_ + dq * 4);
        tile[pt * 65 + dq * 4 + 0] = v.x;
        tile[pt * 65 + dq * 4 + 1] = v.y;
        tile[pt * 65 + dq * 4 + 2] = v.z;
        tile[pt * 65 + dq * 4 + 3] = v.w;
    }
    __syncthreads();

    // Phase B: 4 scalar tile reads -> one float4 store (512 B contiguous per d)
    float* ob = out + (size_t)bb * (D_ * HW_) + hw0;
#pragma unroll
    for (int it = 0; it < 8; ++it) {
        const int e = it * 256 + tid;   // 0..2047
        const int d = e >> 5;           // 0..63
        const int g = e & 31;           // float4 group within 128 pts
        float4 q;
        q.x = tile[(g * 4 + 0) * 65 + d];
        q.y = tile[(g * 4 + 1) * 65 + d];
        q.z = tile[(g * 4 + 2) * 65 + d];
        q.w = tile[(g * 4 + 3) * 65 + d];
        *(float4*)(ob + (size_t)d * HW_ + g * 4) = q;
    }
}

extern "C" void kernel_launch(void* const* d_in, const int* in_sizes, int n_in,
                              void* d_out, int out_size, void* d_ws, size_t ws_size,
                              hipStream_t stream) {
    const float* x  = (const float*)d_in[0];   // (16, 64, 64, 64)
    const float* cb = (const float*)d_in[1];   // (1024, 64)
    float* out   = (float*)d_out;
    float* cnorm = (float*)d_ws;                       // 4 KB
    short* P     = (short*)((char*)d_ws + 4096);       // 256 KB packed bf16 codebook

    vq_pack<<<16, 256, 0, stream>>>(cb, cnorm, P);
    vq_main<<<NPTS_ / 128, 256, 0, stream>>>(x, cb, cnorm, P, out);
}